// Round 1
// 648.720 us; speedup vs baseline: 1.7533x; 1.7533x over previous
//
#include <hip/hip_runtime.h>
#include <hip/hip_bf16.h>

// Encoder: attention-weighted LSTM, B=32768 T=9 D_IN=81 H=128.
// All inputs AND outputs fp32 (round-1 NaN => inputs fp32; round-2
// misalignment error 0.159 > max|ref| => outputs fp32 too).
// Key simplification: logits = pre + scalar(b) broadcast over softmax axis
// => attn = softmax(pre) is time-invariant; Wh/Wc are dead parameters.
// Recurrence reduces to gates_t = [w_in_t | h_t] @ [W_ih | W_hh]^T + bias.
//
// This version: gates GEMM on the MATRIX pipe (MfmaUtil was 0.0 while
// VALUBusy=67% did ~430us of irreducible scalar FMAs).
//   - mfma_f32_16x16x32_bf16, swapped operands: A = W^T tile (M=gate-col p),
//     B = activations^T (N=batch). C/D layout (HW-verified): col=lane&15=batch,
//     row=(lane>>4)*4+reg = p  =>  with col-perm p=4u+q each lane's f32x4 acc
//     is the full {i,f,g,o} quad of one (b,u) pair -> pointwise stays lane-local.
//   - fp32 activation accuracy kept via bf16 hi+lo split planes; each W
//     fragment feeds 2 MFMAs (hi,lo). W itself bf16 as before.
//   - Both operands loaded contiguous-8-along-k from [row][k] buffers, so any
//     internal k-permutation of the fragment layout cancels between A and B.
//   - W pre-transposed to [p][kPad] bf16 row-major: A-fragment = one 16B
//     global load (L2-resident; ~2.1 GB L2 traffic total).
//   - 2 barriers per t (was 28: 14 LDS W-chunks x 2).

namespace {

constexpr int kB    = 32768;
constexpr int kT    = 9;
constexpr int kD    = 81;     // D_IN
constexpr int kH    = 128;
constexpr int kG    = 512;    // 4H
constexpr int kK    = 209;    // 81 + 128
constexpr int kKPad = 224;    // padded to 7 MFMA k-steps of 32 (pad rows zeroed)
constexpr int kNB   = 32;     // batch rows per block
constexpr int kTh   = 256;    // threads per block (4 waves)
constexpr int kAS   = 232;    // LDS activation row stride in bf16:
                              // 464B = 29*16 -> rows 16B-aligned for ds_read_b128,
                              // dword stride 116 == 20 mod 32 -> 2-way bank alias (free)

// ws layout: [Wt2 bf16 [512][224] gate-permuted rows][bias 512 f32][Wx 16 f32][b_attn f32]
constexpr int kWsWtBytes  = kG * kKPad * 2;      // 229376
constexpr int kWsBiasOff  = kWsWtBytes;
constexpr int kWsWxOff    = kWsBiasOff + kG * 4;
constexpr int kWsBAttnOff = kWsWxOff + 16 * 4;

typedef __bf16 bf16x8 __attribute__((ext_vector_type(8)));
typedef float  f32x4  __attribute__((ext_vector_type(4)));

__device__ __forceinline__ float sigf(float x) {
  return __builtin_amdgcn_rcpf(1.f + __expf(-x));
}
// tanh(x) = 1 - 2/(1+e^{2x}); saturates correctly as exp -> 0/inf
__device__ __forceinline__ float tanhfast(float x) {
  return 1.f - 2.f * __builtin_amdgcn_rcpf(1.f + __expf(2.f * x));
}

// ---- prep: repack weights. Row permutation p = u*4+q (gate g = q*128+u) so
// MFMA D-rows (p) give one lane the {i,f,g,o} quad of unit u. W stored
// TRANSPOSED [p][k] bf16 so A-operand fragments (lane: row=l&15, 8 contiguous
// k) are single 16B loads.
__global__ void prep_kernel(const float* __restrict__ W_attn,
                            const float* __restrict__ b_attn,
                            const float* __restrict__ W_ih,
                            const float* __restrict__ W_hh,
                            const float* __restrict__ b_ih,
                            const float* __restrict__ b_hh,
                            unsigned char* __restrict__ ws) {
  __bf16* Wt   = reinterpret_cast<__bf16*>(ws);
  float* biasp = reinterpret_cast<float*>(ws + kWsBiasOff);
  float* wxp   = reinterpret_cast<float*>(ws + kWsWxOff);
  float* bap   = reinterpret_cast<float*>(ws + kWsBAttnOff);
  int tid = blockIdx.x * blockDim.x + threadIdx.x;
  int nth = gridDim.x * blockDim.x;
  for (int idx = tid; idx < kG * kKPad; idx += nth) {
    int p = idx / kKPad, k = idx - p * kKPad;
    int u = p >> 2, q = p & 3, g = q * kH + u;
    float v = 0.f;
    if (k < kD)      v = W_ih[g * kD + k];
    else if (k < kK) v = W_hh[g * kH + (k - kD)];
    Wt[idx] = (__bf16)v;   // idx == p*kKPad + k
  }
  if (tid < kG) {
    int u = tid >> 2, q = tid & 3, g = q * kH + u;
    biasp[tid] = b_ih[g] + b_hh[g];
  }
  if (tid >= kG && tid < kG + 16) {
    int t = tid - kG;
    wxp[t] = (t < kT) ? W_attn[2 * kH + t] : 0.f;
  }
  if (tid == kG + 16) bap[0] = b_attn[0];
}

__global__ __launch_bounds__(kTh, 2) void enc_main(
    const float* __restrict__ x,              // (B,9,81) fp32
    const unsigned char* __restrict__ ws,
    float* __restrict__ out_w,                // (B,9,81) fp32
    float* __restrict__ out_h) {              // (B,9,128) fp32
  // Activations^T stored as [b][k] row-major bf16, hi and lo planes.
  // k<81: w_in, 81..208: h, 209..231: zero pad.
  __shared__ __align__(16) __bf16 ash[kNB][kAS];
  __shared__ __align__(16) __bf16 asl[kNB][kAS];
  __shared__ __align__(16) float bias_s[kG];
  __shared__ float red[kNB][8];
  __shared__ float wx_s[16];
  __shared__ float battn_s;

  const int tid = threadIdx.x;
  const int b0  = blockIdx.x * kNB;
  const __bf16* Wt = reinterpret_cast<const __bf16*>(ws);

  if (tid < 16) wx_s[tid] = reinterpret_cast<const float*>(ws + kWsWxOff)[tid];
  if (tid == 16) battn_s = reinterpret_cast<const float*>(ws + kWsBAttnOff)[0];
  bias_s[tid]       = reinterpret_cast<const float*>(ws + kWsBiasOff)[tid];
  bias_s[tid + 256] = reinterpret_cast<const float*>(ws + kWsBiasOff)[tid + 256];
  for (int i = tid; i < kNB * kAS; i += kTh) {   // zero (h0=0, k-pad=0)
    (&ash[0][0])[i] = (__bf16)0.f;
    (&asl[0][0])[i] = (__bf16)0.f;
  }
  __syncthreads();

  // ---- pre + softmax once (time-invariant). thread: b = tid>>3, d = (tid&7)+8m
  const int sb = tid >> 3;
  const int sq = tid & 7;
  float attn[11];
  {
    float lmax = -3.4e38f;
    const size_t xbase = (size_t)(b0 + sb) * kT * kD;
#pragma unroll
    for (int m = 0; m < 11; ++m) {
      int d = sq + 8 * m;
      float s = -3.4e38f;
      if (d < kD) {
        s = battn_s;
#pragma unroll
        for (int t = 0; t < kT; ++t)
          s += x[xbase + t * kD + d] * wx_s[t];
        lmax = fmaxf(lmax, s);
      }
      attn[m] = s;
    }
    red[sb][sq] = lmax;
    __syncthreads();
    float gmax = red[sb][0];
#pragma unroll
    for (int r = 1; r < 8; ++r) gmax = fmaxf(gmax, red[sb][r]);
    __syncthreads();
    float lsum = 0.f;
#pragma unroll
    for (int m = 0; m < 11; ++m) {
      float e = __expf(attn[m] - gmax);   // invalid lanes: exp(-huge) = 0
      attn[m] = e;
      lsum += e;
    }
    red[sb][sq] = lsum;
    __syncthreads();
    float tot = 0.f;
#pragma unroll
    for (int r = 0; r < 8; ++r) tot += red[sb][r];
    float inv = 1.0f / tot;
#pragma unroll
    for (int m = 0; m < 11; ++m) attn[m] *= inv;
  }

  // ---- MFMA ids: wave wv owns gate-cols p in [wv*128,(wv+1)*128) (8 p-tiles).
  const int lane = tid & 63;
  const int wv   = tid >> 6;
  const int lb   = lane & 15;   // A row within p-tile / B col (batch) / D col
  const int kg   = lane >> 4;   // k-group: k = ks*32 + kg*8 + j
  const __bf16* wrow = Wt + (size_t)(wv * 128 + lb) * kKPad;

  float c_reg[2][8];
#pragma unroll
  for (int bt = 0; bt < 2; ++bt)
#pragma unroll
    for (int p = 0; p < 8; ++p) c_reg[bt][p] = 0.f;

  for (int t = 0; t < kT; ++t) {
    // ---- phase A: w_in = attn * x_t -> hi/lo planes + out_w (fp32 exact)
    {
      const size_t xoff = ((size_t)(b0 + sb) * kT + t) * kD;
#pragma unroll
      for (int m = 0; m < 11; ++m) {
        int d = sq + 8 * m;
        if (d < kD) {
          float w = attn[m] * x[xoff + d];
          out_w[xoff + d] = w;
          __bf16 hi = (__bf16)w;
          ash[sb][d] = hi;
          asl[sb][d] = (__bf16)(w - (float)hi);
        }
      }
    }
    __syncthreads();   // w_in writes (t) + h writes (t-1) visible to all waves

    // ---- gates = bias + act @ W^T via MFMA (acc init = bias quad broadcast)
    f32x4 acc[2][8];
#pragma unroll
    for (int p = 0; p < 8; ++p) {
      f32x4 bv = *reinterpret_cast<const f32x4*>(
          &bias_s[wv * 128 + p * 16 + kg * 4]);
      acc[0][p] = bv;
      acc[1][p] = bv;
    }
#pragma unroll
    for (int ks = 0; ks < kKPad / 32; ++ks) {
      const int k0 = ks * 32 + kg * 8;
      bf16x8 bh0 = *reinterpret_cast<const bf16x8*>(&ash[lb][k0]);
      bf16x8 bl0 = *reinterpret_cast<const bf16x8*>(&asl[lb][k0]);
      bf16x8 bh1 = *reinterpret_cast<const bf16x8*>(&ash[16 + lb][k0]);
      bf16x8 bl1 = *reinterpret_cast<const bf16x8*>(&asl[16 + lb][k0]);
#pragma unroll
      for (int p = 0; p < 8; ++p) {
        bf16x8 wf = *reinterpret_cast<const bf16x8*>(
            wrow + p * (16 * kKPad) + k0);
        acc[0][p] = __builtin_amdgcn_mfma_f32_16x16x32_bf16(wf, bh0, acc[0][p], 0, 0, 0);
        acc[0][p] = __builtin_amdgcn_mfma_f32_16x16x32_bf16(wf, bl0, acc[0][p], 0, 0, 0);
        acc[1][p] = __builtin_amdgcn_mfma_f32_16x16x32_bf16(wf, bh1, acc[1][p], 0, 0, 0);
        acc[1][p] = __builtin_amdgcn_mfma_f32_16x16x32_bf16(wf, bl1, acc[1][p], 0, 0, 0);
      }
    }
    __syncthreads();   // all waves' GEMM reads done before h-region rewrite

    // ---- LSTM pointwise: lane holds {i,f,g,o} (= reg 0..3) of (b,u)
    //      b = bt*16 + lb, u = wv*32 + p*4 + kg; c stays in registers.
#pragma unroll
    for (int bt = 0; bt < 2; ++bt) {
#pragma unroll
      for (int p = 0; p < 8; ++p) {
        f32x4 g4 = acc[bt][p];
        float cn = sigf(g4[1]) * c_reg[bt][p] + sigf(g4[0]) * tanhfast(g4[2]);
        float hn = sigf(g4[3]) * tanhfast(cn);
        c_reg[bt][p] = cn;
        const int b = bt * 16 + lb;
        const int u = wv * 32 + p * 4 + kg;
        out_h[((size_t)(b0 + b) * kT + t) * kH + u] = hn;
        __bf16 hi = (__bf16)hn;
        ash[b][kD + u] = hi;                        // k = 81 + u
        asl[b][kD + u] = (__bf16)(hn - (float)hi);
      }
    }
    // no barrier here: next phase A writes k<81 (disjoint from h region);
    // next iteration's barrier orders h writes before GEMM reads.
  }
}

}  // namespace

extern "C" void kernel_launch(void* const* d_in, const int* in_sizes, int n_in,
                              void* d_out, int out_size, void* d_ws, size_t ws_size,
                              hipStream_t stream) {
  (void)in_sizes; (void)n_in; (void)out_size; (void)ws_size;
  const float* x      = (const float*)d_in[0];
  const float* W_attn = (const float*)d_in[1];
  const float* b_attn = (const float*)d_in[2];
  const float* W_ih   = (const float*)d_in[3];
  const float* W_hh   = (const float*)d_in[4];
  const float* b_ih   = (const float*)d_in[5];
  const float* b_hh   = (const float*)d_in[6];
  float* out_w = (float*)d_out;
  float* out_h = out_w + (size_t)kB * kT * kD;
  unsigned char* ws = (unsigned char*)d_ws;

  hipLaunchKernelGGL(prep_kernel, dim3(64), dim3(256), 0, stream,
                     W_attn, b_attn, W_ih, W_hh, b_ih, b_hh, ws);
  hipLaunchKernelGGL(enc_main, dim3(kB / kNB), dim3(kTh), 0, stream,
                     x, ws, out_w, out_h);
}